// Round 2
// baseline (127.847 us; speedup 1.0000x reference)
//
#include <hip/hip_runtime.h>

typedef _Float16 half8 __attribute__((ext_vector_type(8)));
typedef _Float16 half4v __attribute__((ext_vector_type(4)));
typedef float floatx4 __attribute__((ext_vector_type(4)));
typedef unsigned int uint2v __attribute__((ext_vector_type(2)));

#define NSPLIT 64
#define KS 64
#define DIM 2048
#define NROW 128            // 2*KS rows of T per split
#define BK 128              // k-panel width
#define KSPL 4              // k-chunks per split -> 256 blocks
#define KCH (DIM / KSPL)    // 512
#define NKC_A (KCH / BK)    // 4 panels per block
#define SST 152             // stage row stride (fp16): 304 B, 16B-aligned, 2-way banks (free)
#define GSZ (NROW * NROW)   // 16384 halfs per partial-gram slab (fp16)
#define NBLK (NSPLIT * KSPL)            // 256 blocks
// float-index offsets into ws (slabs are halfs: NBLK*GSZ/2 floats)
#define GT2F_OFF (NBLK * GSZ / 2)       // per-(split,chunk) sum-of-gram scalars (256 floats)
#define PART_OFF (GT2F_OFF + NBLK)      // per-split partials (64 x float4)
#define FLAG_OFF (PART_OFF + 256)       // u32 flags: 192 sibling + 64 split + sentinel@256

// Slab layout fragment-major (half index): idx = wave*1024 + acc*256 + lane*4 + reg
// wave = (row>>5)*4 + (col>>5); acc = ((row>>4)&1)*2 + ((col>>4)&1);
// lane = ((row&15)>>2)*16 + (col&15); reg = row&3.
// rows 32*rb..32*rb+31 of a slab = contiguous half-range [rb*4096, rb*4096+4096).

__device__ __forceinline__ unsigned int pk16(float a, float b) {
  return __builtin_bit_cast(unsigned int, __builtin_amdgcn_cvt_pkrtz(a, b));
}

// ---- Single fused kernel. grid = 256 (all co-resident: 1024 thr, 76KB LDS -> 1 blk/CU).
// Phase 1 (all blocks): partial gram of (split p, k-chunk c). c<3 write fp16 slab to
// global + release flag; c==3 keeps its slab in LDS, spins on sibling flags (poison-
// agnostic magic), then Phase 2: per-split l2/exp reduce, overlapped with other
// splits' gram. Split 0's reducer waits on all 64 split flags and writes outputs.
__global__ __launch_bounds__(1024) void fused_kernel(const float* __restrict__ src,
                                                     const float* __restrict__ tgt,
                                                     float* __restrict__ ws,
                                                     float* __restrict__ out,
                                                     unsigned nonce) {
  __shared__ __align__(16) _Float16 stage[2][NROW * SST];  // 2 x ~38 KB; reused as c3 slab
  __shared__ float red[16];
  __shared__ float sqv[NROW];
  __shared__ float bcast[8];
  __shared__ float redm[16];
  __shared__ float redqA[16];
  __shared__ float redqB[16];
  __shared__ float gsum3;
  __shared__ unsigned smagic;

  const int b = blockIdx.x;
  // XCD-aware remap: siblings (same p, c=0..3) land on the same XCD (b%8 assumed XCD id)
  const int p = (b & 7) | ((b >> 5) << 3);
  const int c = (b >> 3) & 3;
  const int tid = threadIdx.x;
  const int lane = tid & 63;
  const int wave = tid >> 6;

  unsigned* flag1 = (unsigned*)(ws + FLAG_OFF);        // [64*3] sibling release flags
  unsigned* flag2 = flag1 + 192;                       // [64] split-done flags
  if (tid == 0) smagic = flag1[256] ^ (2u * nonce + 1u);  // sentinel ^ odd != sentinel

  const int srow = tid >> 3;
  const int c4 = (tid & 7) * 4;
  const float* rowp = ((srow < KS) ? (src + (size_t)(p * KS + srow) * DIM)
                                   : (tgt + (size_t)(p * KS + (srow - KS)) * DIM)) +
                      c * KCH;

  const int wr = (wave >> 2) * 32;
  const int wc = (wave & 3) * 32;
  const int fr = lane & 15;
  const int fk = (lane >> 4) * 8;

  floatx4 acc00 = {0.f, 0.f, 0.f, 0.f};
  floatx4 acc01 = {0.f, 0.f, 0.f, 0.f};
  floatx4 acc10 = {0.f, 0.f, 0.f, 0.f};
  floatx4 acc11 = {0.f, 0.f, 0.f, 0.f};

  floatx4 f0, f1, f2, f3;
#define LOADK(kc)                                                   \
  do {                                                              \
    const floatx4* gp_ = (const floatx4*)(rowp + (kc)*BK + c4);     \
    f0 = __builtin_nontemporal_load(gp_);                           \
    f1 = __builtin_nontemporal_load(gp_ + 8);                       \
    f2 = __builtin_nontemporal_load(gp_ + 16);                      \
    f3 = __builtin_nontemporal_load(gp_ + 24);                      \
  } while (0)

  LOADK(0);
#pragma unroll
  for (int kc = 0; kc < NKC_A; ++kc) {
    {
      _Float16* sp = &stage[kc & 1][srow * SST + c4];
      *(uint2v*)(sp)      = (uint2v){pk16(f0[0], f0[1]), pk16(f0[2], f0[3])};
      *(uint2v*)(sp + 32) = (uint2v){pk16(f1[0], f1[1]), pk16(f1[2], f1[3])};
      *(uint2v*)(sp + 64) = (uint2v){pk16(f2[0], f2[1]), pk16(f2[2], f2[3])};
      *(uint2v*)(sp + 96) = (uint2v){pk16(f3[0], f3[1]), pk16(f3[2], f3[3])};
    }
    if (kc + 1 < NKC_A) LOADK(kc + 1);  // next panel's loads in flight across barrier
    __syncthreads();
    const _Float16* sbuf = stage[kc & 1];
#pragma unroll
    for (int ks = 0; ks < 4; ++ks) {
      const int ko = ks * 32 + fk;
      half8 a0 = *(const half8*)&sbuf[(wr + fr) * SST + ko];
      half8 a1 = *(const half8*)&sbuf[(wr + 16 + fr) * SST + ko];
      half8 b0 = *(const half8*)&sbuf[(wc + fr) * SST + ko];
      half8 b1 = *(const half8*)&sbuf[(wc + 16 + fr) * SST + ko];
      acc00 = __builtin_amdgcn_mfma_f32_16x16x32_f16(a0, b0, acc00, 0, 0, 0);
      acc01 = __builtin_amdgcn_mfma_f32_16x16x32_f16(a0, b1, acc01, 0, 0, 0);
      acc10 = __builtin_amdgcn_mfma_f32_16x16x32_f16(a1, b0, acc10, 0, 0, 0);
      acc11 = __builtin_amdgcn_mfma_f32_16x16x32_f16(a1, b1, acc11, 0, 0, 0);
    }
  }
#undef LOADK

  // pack fp16 fragments (RNE casts) -- same values both paths
  half4v h0, h1, h2, h3;
#pragma unroll
  for (int r = 0; r < 4; ++r) {
    h0[r] = (_Float16)acc00[r];
    h1[r] = (_Float16)acc01[r];
    h2[r] = (_Float16)acc10[r];
    h3[r] = (_Float16)acc11[r];
  }
  if (c != 3) {  // siblings: fp16 slab to global (fragment-major, 512B/wave stores)
    _Float16* hs = (_Float16*)ws + (size_t)(p * KSPL + c) * GSZ + wave * 1024 + lane * 4;
    *(half4v*)(hs)       = h0;
    *(half4v*)(hs + 256) = h1;
    *(half4v*)(hs + 512) = h2;
    *(half4v*)(hs + 768) = h3;
  }

  // block-reduce fp32 sum of this partial gram
  float gsum = 0.0f;
#pragma unroll
  for (int r = 0; r < 4; ++r) gsum += acc00[r] + acc01[r] + acc10[r] + acc11[r];
#pragma unroll
  for (int m = 1; m <= 32; m <<= 1) gsum += __shfl_xor(gsum, m, 64);
  if (lane == 0) red[wave] = gsum;
  __syncthreads();  // (A) red[] ready; all global slab stores drained; stage free; smagic visible

  float tot = 0.0f;
  if (tid == 0)
    for (int w = 0; w < 16; ++w) tot += red[w];

  if (c != 3) {  // release: gsum + slab visible before flag
    if (tid == 0) {
      ws[GT2F_OFF + p * 4 + c] = tot;
      __threadfence();
      atomicExch(&flag1[p * 3 + c], smagic);
    }
    return;
  }

  // ---- c==3: designated reducer for split p ----
  if (tid == 0) gsum3 = tot;
  _Float16* lsl = (_Float16*)stage;  // own chunk-3 slab kept in LDS (32KB, same layout)
  {
    _Float16* ls = lsl + wave * 1024 + lane * 4;
    *(half4v*)(ls)       = h0;
    *(half4v*)(ls + 256) = h1;
    *(half4v*)(ls + 512) = h2;
    *(half4v*)(ls + 768) = h3;
  }
  const unsigned mg = smagic;
  if (tid < 3) {  // spin on siblings (all blocks resident -> no deadlock)
    while (atomicAdd(&flag1[p * 3 + tid], 0u) != mg) __builtin_amdgcn_s_sleep(1);
  }
  __syncthreads();   // (B) LDS slab ready; siblings released
  __threadfence();   // acquire

  const _Float16* sb = (const _Float16*)ws + (size_t)(p * KSPL) * GSZ;

  // diagonal (sq): same fp16 values + same c8 sum order as strips -> l2_ii exactly 0
  if (tid < NROW) {
    const int i = tid;
    const int wd = (i >> 5) * 5;
    const int ad = ((i >> 4) & 1) * 3;
    const int lnd = (((i & 15) >> 2) << 4) + (i & 15);
    const int idxd = wd * 1024 + ad * 256 + lnd * 4 + (i & 3);
    float d = 0.0f;
#pragma unroll
    for (int c8 = 0; c8 < 3; ++c8) d += (float)sb[(size_t)c8 * GSZ + idxd];
    d += (float)lsl[idxd];
    sqv[i] = d;
  }
  __syncthreads();  // (C)

  if (tid == 0) {
    float ssq = 0.0f;
    for (int i = 0; i < NROW; ++i) ssq += sqv[i];
    float gt = ws[GT2F_OFF + p * 4 + 0] + ws[GT2F_OFF + p * 4 + 1] +
               ws[GT2F_OFF + p * 4 + 2] + gsum3;
    float suml2 = 2.0f * (float)NROW * ssq - 2.0f * gt;      // sum(l2) identity
    float bw = suml2 / (float)(NROW * NROW - NROW) * 0.25f;  // /(n^2-n) /KERNEL_MUL^2
    float mult = 1.0f;
    for (int k = 0; k < 5; ++k) {
      bcast[k] = 1.0f / (bw * mult + 1e-9f);
      mult *= 2.0f;
    }
  }
  __syncthreads();  // (D)

  const float ib0 = bcast[0], ib1 = bcast[1], ib2 = bcast[2], ib3 = bcast[3], ib4 = bcast[4];
  // fragment slot decode (per rb2 strip): row = rb2*32 + bit7*16 + bits5..4*4 + k;
  // col = bits9..8*32 + bit6*16 + bits3..0
  const int r0b = ((tid >> 7) & 1) * 16 + ((tid >> 4) & 3) * 4;
  const int col = (tid >> 8) * 32 + ((tid >> 6) & 1) * 16 + (tid & 15);
  const float sqc = sqv[col];
  float sA = 0.0f, sB = 0.0f, lmax = 0.0f;
#pragma unroll
  for (int rb2 = 0; rb2 < 4; ++rb2) {
    const int off = rb2 * 4096 + tid * 4;
    half4v a0 = *(const half4v*)(sb + off);
    half4v a1 = *(const half4v*)(sb + GSZ + off);
    half4v a2 = *(const half4v*)(sb + 2 * (size_t)GSZ + off);
    half4v a3 = *(const half4v*)(lsl + off);
    const floatx4 sr = *(const floatx4*)&sqv[rb2 * 32 + r0b];
    float qsum = 0.0f;
#pragma unroll
    for (int k = 0; k < 4; ++k) {
      float g = (float)a0[k] + (float)a1[k] + (float)a2[k] + (float)a3[k];
      float v = sr[k] + sqc - 2.0f * g;
      lmax = fmaxf(lmax, v);
      qsum += __expf(-v * ib0) + __expf(-v * ib1) + __expf(-v * ib2) +
              __expf(-v * ib3) + __expf(-v * ib4);
    }
    if (rb2 < 2) sA += qsum; else sB += qsum;
  }
#pragma unroll
  for (int m = 1; m <= 32; m <<= 1) {
    lmax = fmaxf(lmax, __shfl_xor(lmax, m, 64));
    sA += __shfl_xor(sA, m, 64);
    sB += __shfl_xor(sB, m, 64);
  }
  if (lane == 0) { redm[wave] = lmax; redqA[wave] = sA; redqB[wave] = sB; }
  __syncthreads();  // (E)

  if (tid == 0) {
    // waves 0..7 cols X, 8..15 cols Y; sA rows X, sB rows Y
    float xx = 0.f, xy = 0.f, yx = 0.f, yy = 0.f, mx = 0.f;
#pragma unroll
    for (int w = 0; w < 8; ++w) { xx += redqA[w]; yx += redqB[w]; }
#pragma unroll
    for (int w = 8; w < 16; ++w) { xy += redqA[w]; yy += redqB[w]; }
#pragma unroll
    for (int w = 0; w < 16; ++w) mx = fmaxf(mx, redm[w]);
    ((float4*)(ws + PART_OFF))[p] = make_float4(xx, xy, yx, yy);
    if (p == NSPLIT - 1) out[1] = mx;  // max l2 of last split: written directly
    __threadfence();
    atomicExch(&flag2[p], mg);
  }

  if (p == 0 && tid < 64) {  // final combine: wave 0 of split 0's reducer
    while (atomicAdd(&flag2[tid], 0u) != mg) __builtin_amdgcn_s_sleep(1);
    __threadfence();
    float4 pt = ((const float4*)(ws + PART_OFF))[tid];
    float xx = pt.x, xy = pt.y, yx = pt.z, yy = pt.w;
#pragma unroll
    for (int m = 1; m <= 32; m <<= 1) {
      xx += __shfl_xor(xx, m, 64);
      xy += __shfl_xor(xy, m, 64);
      yx += __shfl_xor(yx, m, 64);
      yy += __shfl_xor(yy, m, 64);
    }
    if (tid == 0) {
      const float inv = 1.0f / (4096.0f * 64.0f);  // /(64*64) then /P
      out[0] = (xx + yy - xy - yx) * inv;
      out[2] = xx * inv;
      out[3] = yy * inv;
      out[4] = xy * inv;
      out[5] = yx * inv;
    }
  }
}

extern "C" void kernel_launch(void* const* d_in, const int* in_sizes, int n_in,
                              void* d_out, int out_size, void* d_ws, size_t ws_size,
                              hipStream_t stream) {
  const float* src = (const float*)d_in[0];
  const float* tgt = (const float*)d_in[1];
  float* out = (float*)d_out;
  float* ws = (float*)d_ws;
  static unsigned nonce = 0;  // distinct magic per launch (captured graphs replay one value;
  ++nonce;                    // replays re-poison ws, and stale==fresh data is identical anyway)
  fused_kernel<<<NBLK, 1024, 0, stream>>>(src, tgt, ws, out, nonce);
}

// Round 3
// 110.979 us; speedup vs baseline: 1.1520x; 1.1520x over previous
//
#include <hip/hip_runtime.h>

typedef _Float16 half8 __attribute__((ext_vector_type(8)));
typedef float floatx4 __attribute__((ext_vector_type(4)));
typedef unsigned int uint2v __attribute__((ext_vector_type(2)));

#define NSPLIT 64
#define KS 64
#define DIM 2048
#define NROW 128           // 2*KS rows per split
#define BK 128             // k-panel width
#define NPAN (DIM / BK)    // 16 panels, full K per block
#define SST 152            // stage row stride (fp16): 304 B, 16B-aligned, 2-way banks (free)
// ws float-index offsets (tiny footprint now; all poisoned each iteration)
#define PART_OFF 0         // 64 x float4 per-split partials
#define FLAG_OFF 256       // u32 flag2[64]; sentinel (never written) at [64]

// One block per split. Full 128x128 gram lives in the 16 waves' accumulators
// (16 x 32x32 tiles). No slab, no mid-kernel fences. Epilogue fully in-register.
// Single end-of-kernel release per block (L2 dirty = 1KB -> cheap wbl2), block 0
// spins at the very end (all 64 blocks trivially co-resident on 256 CUs).

__device__ __forceinline__ unsigned int pk16(float a, float b) {
  return __builtin_bit_cast(unsigned int, __builtin_amdgcn_cvt_pkrtz(a, b));
}

__global__ __launch_bounds__(1024) void mmd_kernel(const float* __restrict__ src,
                                                   const float* __restrict__ tgt,
                                                   float* __restrict__ ws,
                                                   float* __restrict__ out,
                                                   unsigned nonce) {
  __shared__ __align__(16) _Float16 stage[2][NROW * SST];  // 2 x ~38 KB
  __shared__ float red[16];
  __shared__ float sqv[NROW];
  __shared__ float bcast[8];
  __shared__ float redm[16];
  __shared__ float redq[16];
  __shared__ unsigned smagic;

  const int p = blockIdx.x;
  const int tid = threadIdx.x;
  const int lane = tid & 63;
  const int wave = tid >> 6;

  unsigned* flag2 = (unsigned*)(ws + FLAG_OFF);
  if (tid == 0) smagic = flag2[64] ^ (2u * nonce + 1u);  // sentinel ^ odd != poison

  const int srow = tid >> 3;           // 0..127: staging row
  const int c4 = (tid & 7) * 4;        // staging col group
  const float* rowp = (srow < KS) ? (src + (size_t)(p * KS + srow) * DIM)
                                  : (tgt + (size_t)(p * KS + (srow - KS)) * DIM);

  const int wr = (wave >> 2) * 32;     // tile row origin
  const int wc = (wave & 3) * 32;      // tile col origin
  const int fr = lane & 15;
  const int fk = (lane >> 4) * 8;

  floatx4 acc00 = {0.f, 0.f, 0.f, 0.f};
  floatx4 acc01 = {0.f, 0.f, 0.f, 0.f};
  floatx4 acc10 = {0.f, 0.f, 0.f, 0.f};
  floatx4 acc11 = {0.f, 0.f, 0.f, 0.f};

  // two register prefetch sets: 2 panels (8 KB/wave) in flight to cover HBM latency
  floatx4 fA0, fA1, fA2, fA3, fB0, fB1, fB2, fB3;
#define LOADK(kc, F0, F1, F2, F3)                                   \
  do {                                                              \
    const floatx4* gp_ = (const floatx4*)(rowp + (kc)*BK + c4);     \
    F0 = gp_[0]; F1 = gp_[8]; F2 = gp_[16]; F3 = gp_[24];           \
  } while (0)
#define STOREP(kc, F0, F1, F2, F3)                                          \
  do {                                                                      \
    _Float16* sp = &stage[(kc) & 1][srow * SST + c4];                       \
    *(uint2v*)(sp)      = (uint2v){pk16(F0[0], F0[1]), pk16(F0[2], F0[3])}; \
    *(uint2v*)(sp + 32) = (uint2v){pk16(F1[0], F1[1]), pk16(F1[2], F1[3])}; \
    *(uint2v*)(sp + 64) = (uint2v){pk16(F2[0], F2[1]), pk16(F2[2], F2[3])}; \
    *(uint2v*)(sp + 96) = (uint2v){pk16(F3[0], F3[1]), pk16(F3[2], F3[3])}; \
  } while (0)
#define MFMAP(kc)                                                            \
  do {                                                                       \
    const _Float16* sbuf = stage[(kc) & 1];                                  \
    _Pragma("unroll") for (int ks = 0; ks < 4; ++ks) {                       \
      const int ko = ks * 32 + fk;                                           \
      half8 a0 = *(const half8*)&sbuf[(wr + fr) * SST + ko];                 \
      half8 a1 = *(const half8*)&sbuf[(wr + 16 + fr) * SST + ko];            \
      half8 b0 = *(const half8*)&sbuf[(wc + fr) * SST + ko];                 \
      half8 b1 = *(const half8*)&sbuf[(wc + 16 + fr) * SST + ko];            \
      acc00 = __builtin_amdgcn_mfma_f32_16x16x32_f16(a0, b0, acc00, 0, 0, 0);\
      acc01 = __builtin_amdgcn_mfma_f32_16x16x32_f16(a0, b1, acc01, 0, 0, 0);\
      acc10 = __builtin_amdgcn_mfma_f32_16x16x32_f16(a1, b0, acc10, 0, 0, 0);\
      acc11 = __builtin_amdgcn_mfma_f32_16x16x32_f16(a1, b1, acc11, 0, 0, 0);\
    }                                                                        \
  } while (0)

  LOADK(0, fA0, fA1, fA2, fA3);
  LOADK(1, fB0, fB1, fB2, fB3);
#pragma unroll
  for (int kc2 = 0; kc2 < NPAN / 2; ++kc2) {
    const int kc = kc2 * 2;
    // barrier invariant (1 barrier/panel): wave V's reads of stage[k&1] (MFMAP(k))
    // precede barrier(k+1) in V's program order; any wave's store to stage[k&1]
    // (STOREP(k+2)) follows barrier(k+1) -> safe, same as the verified R1 loop.
    STOREP(kc, fA0, fA1, fA2, fA3);                      // waits only on its own loads
    if (kc + 2 < NPAN) LOADK(kc + 2, fA0, fA1, fA2, fA3);
    __syncthreads();
    MFMAP(kc);
    STOREP(kc + 1, fB0, fB1, fB2, fB3);
    if (kc + 3 < NPAN) LOADK(kc + 3, fB0, fB1, fB2, fB3);
    __syncthreads();
    MFMAP(kc + 1);
  }
#undef LOADK
#undef STOREP
#undef MFMAP

  // ---- sq from diag accumulators (fp32, exact: l2_ii = 2a - 2a = 0) ----
  // C/D layout: row_local = (lane>>4)*4 + reg, col_local = lane&15.
  if (wr == wc) {
    const int q = lane >> 4;
    if ((fr >> 2) == q) {                 // this lane holds diag elements
      const int s = lane & 3;             // reg index of the diag element
      sqv[wr + fr] = acc00[s];            // rows/cols wr+fr
      sqv[wr + 16 + fr] = acc11[s];       // rows/cols wr+16+fr
    }
  }

  // ---- sum(gram): block shuffle-reduce of all accumulators ----
  float gsum = 0.0f;
#pragma unroll
  for (int r = 0; r < 4; ++r) gsum += acc00[r] + acc01[r] + acc10[r] + acc11[r];
#pragma unroll
  for (int m = 1; m <= 32; m <<= 1) gsum += __shfl_xor(gsum, m, 64);
  if (lane == 0) red[wave] = gsum;
  __syncthreads();  // sqv + red complete

  if (tid == 0) {
    float ssq = 0.0f;
    for (int i = 0; i < NROW; ++i) ssq += sqv[i];
    float gt = 0.0f;
    for (int w = 0; w < 16; ++w) gt += red[w];
    float suml2 = 2.0f * (float)NROW * ssq - 2.0f * gt;      // sum(l2) identity
    float bw = suml2 / (float)(NROW * NROW - NROW) * 0.25f;  // /(n^2-n) /KERNEL_MUL^2
    float mult = 1.0f;
    for (int k = 0; k < 5; ++k) {
      bcast[k] = 1.0f / (bw * mult + 1e-9f);
      mult *= 2.0f;
    }
  }
  __syncthreads();

  // ---- in-register epilogue: l2 + 5-bw exp sums over this wave's 32x32 tile ----
  const float ib0 = bcast[0], ib1 = bcast[1], ib2 = bcast[2], ib3 = bcast[3], ib4 = bcast[4];
  const int r0 = wr + (lane >> 4) * 4;
  const floatx4 sr0 = *(const floatx4*)&sqv[r0];        // rows r0..r0+3 (16B aligned)
  const floatx4 sr1 = *(const floatx4*)&sqv[r0 + 16];
  const float sc0 = sqv[wc + fr];
  const float sc1 = sqv[wc + 16 + fr];
  float qsum = 0.0f, lmax = 0.0f;
#pragma unroll
  for (int k = 0; k < 4; ++k) {
    const float v00 = sr0[k] + sc0 - 2.0f * acc00[k];
    const float v01 = sr0[k] + sc1 - 2.0f * acc01[k];
    const float v10 = sr1[k] + sc0 - 2.0f * acc10[k];
    const float v11 = sr1[k] + sc1 - 2.0f * acc11[k];
    lmax = fmaxf(fmaxf(lmax, fmaxf(v00, v01)), fmaxf(v10, v11));
    qsum += __expf(-v00 * ib0) + __expf(-v00 * ib1) + __expf(-v00 * ib2) +
            __expf(-v00 * ib3) + __expf(-v00 * ib4);
    qsum += __expf(-v01 * ib0) + __expf(-v01 * ib1) + __expf(-v01 * ib2) +
            __expf(-v01 * ib3) + __expf(-v01 * ib4);
    qsum += __expf(-v10 * ib0) + __expf(-v10 * ib1) + __expf(-v10 * ib2) +
            __expf(-v10 * ib3) + __expf(-v10 * ib4);
    qsum += __expf(-v11 * ib0) + __expf(-v11 * ib1) + __expf(-v11 * ib2) +
            __expf(-v11 * ib3) + __expf(-v11 * ib4);
  }
#pragma unroll
  for (int m = 1; m <= 32; m <<= 1) {
    qsum += __shfl_xor(qsum, m, 64);
    lmax = fmaxf(lmax, __shfl_xor(lmax, m, 64));
  }
  if (lane == 0) { redq[wave] = qsum; redm[wave] = lmax; }
  __syncthreads();

  if (tid == 0) {
    // wave w tile: rows X iff (w>>2)<2, cols X iff (w&3)<2 (32x32 tiles never straddle 64)
    float xx = 0.f, xy = 0.f, yx = 0.f, yy = 0.f, mx = 0.f;
    for (int w = 0; w < 16; ++w) {
      const float v = redq[w];
      const bool rX = (w >> 2) < 2, cX = (w & 3) < 2;
      if (rX && cX) xx += v;
      else if (rX) xy += v;
      else if (cX) yx += v;
      else yy += v;
      mx = fmaxf(mx, redm[w]);
    }
    ((float4*)(ws + PART_OFF))[p] = make_float4(xx, xy, yx, yy);
    if (p == NSPLIT - 1) out[1] = mx;  // max l2 of last split
    __threadfence();                   // release (L2 dirty = 1KB partials: cheap)
    atomicExch(&flag2[p], smagic);
  }

  // ---- final combine: wave 0 of block 0 (end-of-kernel spin; all 64 resident) ----
  if (p == 0 && wave == 0) {
    const unsigned mg = smagic;
    while (atomicAdd(&flag2[lane], 0u) != mg) __builtin_amdgcn_s_sleep(4);
    __threadfence();  // acquire
    float4 pt = ((const float4*)(ws + PART_OFF))[lane];
    float xx = pt.x, xy = pt.y, yx = pt.z, yy = pt.w;
#pragma unroll
    for (int m = 1; m <= 32; m <<= 1) {
      xx += __shfl_xor(xx, m, 64);
      xy += __shfl_xor(xy, m, 64);
      yx += __shfl_xor(yx, m, 64);
      yy += __shfl_xor(yy, m, 64);
    }
    if (lane == 0) {
      const float inv = 1.0f / (4096.0f * 64.0f);  // /(64*64) then /P
      out[0] = (xx + yy - xy - yx) * inv;
      out[2] = xx * inv;
      out[3] = yy * inv;
      out[4] = xy * inv;
      out[5] = yx * inv;
    }
  }
}

extern "C" void kernel_launch(void* const* d_in, const int* in_sizes, int n_in,
                              void* d_out, int out_size, void* d_ws, size_t ws_size,
                              hipStream_t stream) {
  const float* src = (const float*)d_in[0];
  const float* tgt = (const float*)d_in[1];
  float* out = (float*)d_out;
  float* ws = (float*)d_ws;
  static unsigned nonce = 0;  // magic != current poison even on graph replay
  ++nonce;
  mmd_kernel<<<NSPLIT, 1024, 0, stream>>>(src, tgt, ws, out, nonce);
}